// Round 4
// baseline (439.923 us; speedup 1.0000x reference)
//
#include <hip/hip_runtime.h>

typedef _Float16 half8v __attribute__((ext_vector_type(8)));
typedef float f32x4 __attribute__((ext_vector_type(4)));

constexpr float INV4096 = 1.0f / 4096.0f;
constexpr float ALPHA = 10.0f;

__device__ __forceinline__ f32x4 mfma16(half8v a, half8v b, f32x4 c_) {
  return __builtin_amdgcn_mfma_f32_16x16x32_f16(a, b, c_, 0, 0, 0);
}

// ---- pre-split: GW (64x1024) and WN (64x64) -> fragment-ready fp16 hi/lo ----
// Fragment for (kc, ks, t): 64 lanes x 16B, lane (q*16+c) holds
// B[e=16t+c][k = kc*64 + ks*32 + q*8 .. +8].
// GW image: hi at kc*16384 + (ks*4+t)*2048 + lane*16, lo at +1024.
// WN image: hi at 262144 + (ks*4+t)*2048 + lane*16, lo at +1024
//   (B[e'][kdim=e] = WN[e][e'] -> transposed gather).
__global__ __launch_bounds__(256) void presplit(const float *__restrict__ GW,
                                                const float *__restrict__ WN,
                                                char *__restrict__ ws) {
  const int gid = blockIdx.x * 256 + threadIdx.x;
  if (gid < 8192) {  // GW: 64 experts x 128 pieces of 8 k
    int e = gid >> 7, kp = gid & 127, k = kp * 8;
    int kc = k >> 6, ks = (k >> 5) & 1, q = (k >> 3) & 3;
    int t = e >> 4, lane = q * 16 + (e & 15);
    const float *src = GW + (size_t)e * 1024 + k;
    f32x4 v0 = *(const f32x4 *)src, v1 = *(const f32x4 *)(src + 4);
    half8v h, l;
#pragma unroll
    for (int j = 0; j < 8; ++j) {
      float vv = j < 4 ? v0[j] : v1[j - 4];
      _Float16 hh = (_Float16)vv;
      h[j] = hh;
      l[j] = (_Float16)((vv - (float)hh) * 4096.0f);
    }
    size_t dst = (size_t)kc * 16384 + (ks * 4 + t) * 2048 + lane * 16;
    *(half8v *)(ws + dst) = h;
    *(half8v *)(ws + dst + 1024) = l;
  } else if (gid < 8704) {  // WN: 64 experts x 8 pieces of 8 k
    int idx = gid - 8192;
    int e = idx >> 3, k = (idx & 7) * 8;
    int ks = (k >> 5) & 1, q = (k >> 3) & 3;
    int t = e >> 4, lane = q * 16 + (e & 15);
    half8v h, l;
#pragma unroll
    for (int j = 0; j < 8; ++j) {
      float vv = WN[(size_t)(k + j) * 64 + e];  // B[e][k+j] = WN[k+j][e]
      _Float16 hh = (_Float16)vv;
      h[j] = hh;
      l[j] = (_Float16)((vv - (float)hh) * 4096.0f);
    }
    size_t dst = 262144 + (size_t)(ks * 4 + t) * 2048 + lane * 16;
    *(half8v *)(ws + dst) = h;
    *(half8v *)(ws + dst + 1024) = l;
  }
}

// Barrier-free main kernel: each wave owns 16 rows, fully independent.
// B fragments stream L2->VGPR (no LDS staging, no s_barrier anywhere).
// LDS: 4KB per wave (16KB/block) only for the same-wave phase-2 transpose.
__global__ __launch_bounds__(256, 3) void topk_gating(
    const float *__restrict__ X, const char *__restrict__ WS,
    const float *__restrict__ GB, const float *__restrict__ NZ,
    float *__restrict__ OUT) {
  __shared__ __align__(16) char lds[16384];
  const int tid = threadIdx.x, lane = tid & 63, wv = tid >> 6;
  const int q = lane >> 4, c = lane & 15;
  const int waveRow = blockIdx.x * 64 + wv * 16;
  const float *xBase = X + (size_t)(waveRow + c) * 1024 + q * 8;
  const char *wsF = WS + lane * 16;

  f32x4 accH[4] = {}, accX[4] = {};
  f32x4 aA[4], aB[4];
  half8v b0h[4], b0l[4], b1h[4], b1l[4];

#define LDA4(dst, p)                     \
  {                                      \
    dst[0] = *(const f32x4 *)((p));      \
    dst[1] = *(const f32x4 *)((p) + 4);  \
    dst[2] = *(const f32x4 *)((p) + 32); \
    dst[3] = *(const f32x4 *)((p) + 36); \
  }
#define LDB(KC, KS, BH, BL)                                        \
  {                                                                \
    _Pragma("unroll") for (int t_ = 0; t_ < 4; ++t_) {             \
      const char *p_ = wsF + (KC)*16384 + ((KS)*4 + t_) * 2048;    \
      BH[t_] = *(const half8v *)p_;                                \
      BL[t_] = *(const half8v *)(p_ + 1024);                       \
    }                                                              \
  }
#define CONV(A, ah, al)                                       \
  {                                                           \
    _Pragma("unroll") for (int ks_ = 0; ks_ < 2; ++ks_)       \
        _Pragma("unroll") for (int j_ = 0; j_ < 8; ++j_) {    \
      float xv_ = A[ks_ * 2 + (j_ >> 2)][j_ & 3];             \
      _Float16 hh_ = (_Float16)xv_;                           \
      ah[ks_][j_] = hh_;                                      \
      al[ks_][j_] = (_Float16)((xv_ - (float)hh_) * 4096.0f); \
    }                                                         \
  }
#define MF(AH, AL, BH, BL)                             \
  {                                                    \
    _Pragma("unroll") for (int t_ = 0; t_ < 4; ++t_) { \
      accH[t_] = mfma16(AH, BH[t_], accH[t_]);         \
      accX[t_] = mfma16(AH, BL[t_], accX[t_]);         \
      accX[t_] = mfma16(AL, BH[t_], accX[t_]);         \
    }                                                  \
  }
// One K-step. A prefetched 1 iter ahead (2 banks); B double-buffered at
// half-iter (ks) granularity. All waits are compiler-managed per-wave vmcnt.
#define STEP(KC, ACUR, ANXT)                                \
  {                                                         \
    if ((KC) + 1 < 16) LDA4(ANXT, xBase + ((KC) + 1) * 64); \
    half8v ah[2], al[2];                                    \
    CONV(ACUR, ah, al);                                     \
    LDB((KC), 1, b1h, b1l);                                 \
    MF(ah[0], al[0], b0h, b0l);                             \
    if ((KC) + 1 < 16) LDB((KC) + 1, 0, b0h, b0l);          \
    MF(ah[1], al[1], b1h, b1l);                             \
  }

  LDA4(aA, xBase);
  LDB(0, 0, b0h, b0l);
  STEP(0, aA, aB)
  STEP(1, aB, aA)
  STEP(2, aA, aB)
  STEP(3, aB, aA)
  STEP(4, aA, aB)
  STEP(5, aB, aA)
  STEP(6, aA, aB)
  STEP(7, aB, aA)
  STEP(8, aA, aB)
  STEP(9, aB, aA)
  STEP(10, aA, aB)
  STEP(11, aB, aA)
  STEP(12, aA, aB)
  STEP(13, aB, aA)
  STEP(14, aA, aB)
  STEP(15, aB, aA)

  // ---- epilogue (still barrier-free; all loads issued up front) ----
  float bs0 = GB[c], bs1 = GB[16 + c], bs2 = GB[32 + c], bs3 = GB[48 + c];
  half8v wnh[8], wnl[8];
#pragma unroll
  for (int ks = 0; ks < 2; ++ks)
#pragma unroll
    for (int t = 0; t < 4; ++t) {
      const char *p = wsF + 262144 + (ks * 4 + t) * 2048;
      wnh[ks * 4 + t] = *(const half8v *)p;
      wnl[ks * 4 + t] = *(const half8v *)(p + 1024);
    }
  float nz[4][4];
#pragma unroll
  for (int t = 0; t < 4; ++t)
#pragma unroll
    for (int r = 0; r < 4; ++r)
      nz[t][r] = NZ[(size_t)(waveRow + 4 * q + r) * 64 + t * 16 + c];

  float cl[4][4];  // [etile][reg]; element = (row 4q+r, expert 16t+c)
  const float bsv[4] = {bs0, bs1, bs2, bs3};
#pragma unroll
  for (int t = 0; t < 4; ++t)
#pragma unroll
    for (int r = 0; r < 4; ++r)
      cl[t][r] = accH[t][r] + accX[t][r] * INV4096 + bsv[t];

  // clean tile -> own-wave LDS region, swizzled (same-wave use: no barrier)
  char *cb = lds + wv * 4096;
#pragma unroll
  for (int t = 0; t < 4; ++t)
#pragma unroll
    for (int r = 0; r < 4; ++r) {
      int row = 4 * q + r;
      int colf = t * 16 + c;
      int off = row * 256 + ((((colf >> 2) ^ row)) << 4) + ((colf & 3) << 2);
      *reinterpret_cast<float *>(cb + off) = cl[t][r];
    }

  // phase 2: raw = clean @ w_noise (split-fp16 MFMA, K=64)
  f32x4 rH[4] = {};
  f32x4 rX[4] = {};
#pragma unroll
  for (int ks = 0; ks < 2; ++ks) {
    int slot0 = ks * 8 + q * 2;
    f32x4 va = *reinterpret_cast<f32x4 *>(cb + c * 256 + (((slot0 ^ c)) << 4));
    f32x4 vb =
        *reinterpret_cast<f32x4 *>(cb + c * 256 + ((((slot0 + 1) ^ c)) << 4));
    half8v ah, al;
#pragma unroll
    for (int j = 0; j < 4; ++j) {
      float v = va[j];
      _Float16 hh = (_Float16)v;
      ah[j] = hh;
      al[j] = (_Float16)((v - (float)hh) * 4096.0f);
      float v2 = vb[j];
      _Float16 h2 = (_Float16)v2;
      ah[4 + j] = h2;
      al[4 + j] = (_Float16)((v2 - (float)h2) * 4096.0f);
    }
#pragma unroll
    for (int t = 0; t < 4; ++t) {
      rH[t] = mfma16(ah, wnh[ks * 4 + t], rH[t]);
      rX[t] = mfma16(ah, wnl[ks * 4 + t], rX[t]);
      rX[t] = mfma16(al, wnh[ks * 4 + t], rX[t]);
    }
  }

  float lg[4][4];  // [r][t]
#pragma unroll
  for (int t = 0; t < 4; ++t)
#pragma unroll
    for (int r = 0; r < 4; ++r) {
      float raw = rH[t][r] + rX[t][r] * INV4096;
      float sp = fmaxf(raw, 0.0f) + __logf(1.0f + __expf(-fabsf(raw)));
      lg[r][t] = cl[t][r] + nz[t][r] * (sp + 1e-5f);
    }

#pragma unroll
  for (int r = 0; r < 4; ++r) {
    float v0 = lg[r][0], v1 = lg[r][1], v2 = lg[r][2], v3 = lg[r][3];
    // top-2: in-lane over 4, then xor-shuffle over the 16-lane group
    float a = fmaxf(v0, v1), b_ = fminf(v0, v1);
    float d1 = fmaxf(v2, v3), d2 = fminf(v2, v3);
    float m1 = fmaxf(a, d1);
    float m2 = fmaxf(fminf(a, d1), fmaxf(b_, d2));
#pragma unroll
    for (int s = 1; s <= 8; s <<= 1) {
      float om1 = __shfl_xor(m1, s, 64);
      float om2 = __shfl_xor(m2, s, 64);
      float hi = fmaxf(m1, om1);
      float lo = fminf(m1, om1);
      float sec = (m1 >= om1) ? m2 : om2;
      m2 = fmaxf(lo, sec);
      m1 = hi;
    }
    // softmax(logits)
    float se[4], ssum = 0.f;
#pragma unroll
    for (int t = 0; t < 4; ++t) {
      se[t] = __expf(lg[r][t] - m1);
      ssum += se[t];
    }
#pragma unroll
    for (int s = 1; s <= 8; s <<= 1) ssum += __shfl_xor(ssum, s, 64);
    float inv = 1.0f / ssum;
    float ov[4];
#pragma unroll
    for (int t = 0; t < 4; ++t) {
      float sm = se[t] * inv;
      float vlog = ALPHA * __logf(1.0f + sm);
      float vexp = ALPHA * (__expf(sm) - 1.0f);
      ov[t] = (lg[r][t] < m2) ? vlog : vexp;
    }
    // gates = softmax(out)
    float g = fmaxf(fmaxf(ov[0], ov[1]), fmaxf(ov[2], ov[3]));
#pragma unroll
    for (int s = 1; s <= 8; s <<= 1) g = fmaxf(g, __shfl_xor(g, s, 64));
    float gsum = 0.f;
#pragma unroll
    for (int t = 0; t < 4; ++t) {
      ov[t] = __expf(ov[t] - g);
      gsum += ov[t];
    }
#pragma unroll
    for (int s = 1; s <= 8; s <<= 1) gsum += __shfl_xor(gsum, s, 64);
    float ginv = 1.0f / gsum;
    size_t rowOff = (size_t)(waveRow + 4 * q + r) * 64;
#pragma unroll
    for (int t = 0; t < 4; ++t)
      OUT[rowOff + t * 16 + c] = ov[t] * ginv;
  }
}

extern "C" void kernel_launch(void *const *d_in, const int *in_sizes, int n_in,
                              void *d_out, int out_size, void *d_ws,
                              size_t ws_size, hipStream_t stream) {
  const float *x = (const float *)d_in[0];
  const float *gw = (const float *)d_in[1];
  const float *gb = (const float *)d_in[2];
  const float *wn = (const float *)d_in[3];
  const float *nz = (const float *)d_in[4];
  float *out = (float *)d_out;
  char *ws = (char *)d_ws;
  const int N = in_sizes[0] / 1024;

  hipLaunchKernelGGL(presplit, dim3(34), dim3(256), 0, stream, gw, wn, ws);
  hipLaunchKernelGGL(topk_gating, dim3(N / 64), dim3(256), 0, stream, x, ws,
                     gb, nz, out);
}

// Round 5
// 270.840 us; speedup vs baseline: 1.6243x; 1.6243x over previous
//
#include <hip/hip_runtime.h>

typedef _Float16 half8v __attribute__((ext_vector_type(8)));
typedef float f32x4 __attribute__((ext_vector_type(4)));

constexpr float INV4096 = 1.0f / 4096.0f;
constexpr float ALPHA = 10.0f;

__device__ __forceinline__ f32x4 mfma16(half8v a, half8v b, f32x4 c_) {
  return __builtin_amdgcn_mfma_f32_16x16x32_f16(a, b, c_, 0, 0, 0);
}
__device__ __forceinline__ void dma16(const void *g, void *l) {
  __builtin_amdgcn_global_load_lds(
      (const __attribute__((address_space(1))) void *)g,
      (__attribute__((address_space(3))) void *)l, 16, 0, 0);
}
template <int N> __device__ __forceinline__ void wait_vm() {
  asm volatile("s_waitcnt vmcnt(%0)" ::"n"(N) : "memory");
}

// ---- pre-split kernel: GW (64x1024 f32) and WN (64x64 f32) -> fp16 hi/lo ----
// ws image (bytes):
//   [0, 262144)        GW: 16 chunks x 16KB; chunk ck: hi[e][kk] at
//                      ck*16384 + e*128 + (((kk>>3)^(e&7))<<4) + (kk&7)*2, lo at +8192
//   [262144, 278528)   WN: same layout, single 16KB image (k = 0..63)
__global__ __launch_bounds__(256) void presplit(const float *__restrict__ GW,
                                                const float *__restrict__ WN,
                                                char *__restrict__ ws) {
  const int b = blockIdx.x;
  const int tid = threadIdx.x;
  if (b < 64) {
    int idx = b * 256 + tid;  // f32x4 index into GW
    int e = idx >> 8;
    int c4 = idx & 255;
    f32x4 v = *reinterpret_cast<const f32x4 *>(GW + (size_t)idx * 4);
#pragma unroll
    for (int j = 0; j < 4; ++j) {
      int k = c4 * 4 + j;
      float vv = v[j];
      _Float16 hh = (_Float16)vv;
      _Float16 ll = (_Float16)((vv - (float)hh) * 4096.0f);
      int ck = k >> 6, kk = k & 63;
      int off = ck * 16384 + e * 128 + ((((kk >> 3) ^ (e & 7))) << 4) + ((kk & 7) << 1);
      *reinterpret_cast<_Float16 *>(ws + off) = hh;
      *reinterpret_cast<_Float16 *>(ws + off + 8192) = ll;
    }
  } else {
    int idx = (b - 64) * 256 + tid;  // f32x4 index into WN [k][e0..e0+3]
    int k = idx >> 4;
    int e0 = (idx & 15) << 2;
    f32x4 v = *reinterpret_cast<const f32x4 *>(WN + (size_t)k * 64 + e0);
#pragma unroll
    for (int j = 0; j < 4; ++j) {
      int e = e0 + j;
      float vv = v[j];
      _Float16 hh = (_Float16)vv;
      _Float16 ll = (_Float16)((vv - (float)hh) * 4096.0f);
      int off = 262144 + e * 128 + ((((k >> 3) ^ (e & 7))) << 4) + ((k & 7) << 1);
      *reinterpret_cast<_Float16 *>(ws + off) = hh;
      *reinterpret_cast<_Float16 *>(ws + off + 8192) = ll;
    }
  }
}

// LDS map (48 KB): 3 B-buffers of 16 KB each; iteration i uses buf[i%3].
// K-chunk order is ROTATED per block: iteration i processes chunk
// ck = (kc0 + i) & 15, kc0 = (blockIdx.x*7)&15 — decorrelates the 4KB-stride
// X passes across blocks at the DRAM-channel level. Sum over K is
// order-independent.
// Epilogue aliases: WN image -> buf1 [16384,32768); clean tile -> buf2, wave w
// region at 32768 + w*4096.
__global__ __launch_bounds__(256, 3) void topk_gating(
    const float *__restrict__ X, const char *__restrict__ WS,
    const float *__restrict__ GB, const float *__restrict__ NZ,
    float *__restrict__ OUT) {
  __shared__ __align__(16) char lds[49152];
  const int tid = threadIdx.x;
  const int lane = tid & 63;
  const int wv = tid >> 6;
  const int q = lane >> 4;  // 0..3
  const int c = lane & 15;  // 0..15
  const int waveRow = blockIdx.x * 64 + wv * 16;
  const int kc0 = (blockIdx.x * 7) & 15;

  f32x4 accH[4] = {};
  f32x4 accX[4] = {};
  f32x4 a0[4], a1[4], a2[4];  // 3 named A banks; iteration i uses bank i%3

  const float *xBase = X + (size_t)(waveRow + c) * 1024 + q * 8;
  const char *wsL = WS + wv * 1024 + lane * 16;  // per-lane global src base
  char *ldsL = lds + wv * 1024;                  // DMA dest (lane off implicit)

#define LDA4(dst, p)                        \
  {                                         \
    dst[0] = *(const f32x4 *)((p) + 0);     \
    dst[1] = *(const f32x4 *)((p) + 4);     \
    dst[2] = *(const f32x4 *)((p) + 32);    \
    dst[3] = *(const f32x4 *)((p) + 36);    \
  }
// DMAB(I): stage rotated chunk ((kc0+I)&15) into buf[I%3]
#define DMAB(I)                                                             \
  {                                                                         \
    int ck_ = (kc0 + (I)) & 15;                                             \
    _Pragma("unroll") for (int i_ = 0; i_ < 4; ++i_)                        \
        dma16(wsL + ck_ * 16384 + i_ * 4096,                                \
              ldsL + ((I) % 3) * 16384 + i_ * 4096);                        \
  }
#define CONV(A, ah, al)                                           \
  {                                                               \
    _Pragma("unroll") for (int ks_ = 0; ks_ < 2; ++ks_)           \
        _Pragma("unroll") for (int j_ = 0; j_ < 8; ++j_) {        \
      float xv_ = A[ks_ * 2 + (j_ >> 2)][j_ & 3];                 \
      _Float16 hh_ = (_Float16)xv_;                               \
      ah[ks_][j_] = hh_;                                          \
      al[ks_][j_] = (_Float16)((xv_ - (float)hh_) * 4096.0f);     \
    }                                                             \
  }
#define MFMAB(BUF, ah, al)                                                 \
  {                                                                        \
    _Pragma("unroll") for (int ks_ = 0; ks_ < 2; ++ks_)                    \
        _Pragma("unroll") for (int t_ = 0; t_ < 4; ++t_) {                 \
      int e_ = t_ * 16 + c;                                                \
      int off_ = (BUF) + e_ * 128 + ((((ks_ * 4 + q) ^ (e_ & 7))) << 4);   \
      half8v bh_ = *reinterpret_cast<half8v *>(lds + off_);                \
      half8v bl_ = *reinterpret_cast<half8v *>(lds + off_ + 8192);         \
      accH[t_] = mfma16(ah[ks_], bh_, accH[t_]);                           \
      accX[t_] = mfma16(ah[ks_], bl_, accX[t_]);                           \
      accX[t_] = mfma16(al[ks_], bh_, accX[t_]);                           \
    }                                                                      \
  }
// One K-step (iteration index KC). Issues B(KC+2) and A(KC+3) (when they
// exist) BEFORE the MFMA block; the following counted vmcnt drains exactly
// through B(KC+1), keeping the 12 youngest ops (A+2, B+1 chunks) in flight
// across the barrier.
#define STEP(KC, ABANK)                                                    \
  {                                                                        \
    half8v ah[2], al[2];                                                   \
    CONV(ABANK, ah, al);                                                   \
    if ((KC) + 2 <= 15) DMAB((KC) + 2);                                    \
    if ((KC) + 3 <= 15)                                                    \
      LDA4(ABANK, xBase + ((kc0 + (KC) + 3) & 15) * 64);                   \
    MFMAB(((KC) % 3) * 16384, ah, al);                                     \
  }
#define BAR() __builtin_amdgcn_s_barrier()

  // prologue: chunks i=0,1 -> buf0,buf1; A(i=0..2) into banks; publish buf0
  DMAB(0);
  DMAB(1);
  LDA4(a0, xBase + kc0 * 64);
  LDA4(a1, xBase + ((kc0 + 1) & 15) * 64);
  LDA4(a2, xBase + ((kc0 + 2) & 15) * 64);
  wait_vm<16>();  // drains B0; leaves B1,A0,A1,A2 in flight
  BAR();

  STEP(0, a0)  wait_vm<12>(); BAR();
  STEP(1, a1)  wait_vm<12>(); BAR();
  STEP(2, a2)  wait_vm<12>(); BAR();
  STEP(3, a0)  wait_vm<12>(); BAR();
  STEP(4, a1)  wait_vm<12>(); BAR();
  STEP(5, a2)  wait_vm<12>(); BAR();
  STEP(6, a0)  wait_vm<12>(); BAR();
  STEP(7, a1)  wait_vm<12>(); BAR();
  STEP(8, a2)  wait_vm<12>(); BAR();
  STEP(9, a0)  wait_vm<12>(); BAR();
  STEP(10, a1) wait_vm<12>(); BAR();
  STEP(11, a2) wait_vm<12>(); BAR();
  STEP(12, a0) wait_vm<12>(); BAR();
  STEP(13, a1) wait_vm<8>();  BAR();  // drains B14; leaves A15,B15
  STEP(14, a2) wait_vm<0>();  BAR();  // last publish (buf0 = B15)
  STEP(15, a0)                        // no barrier: epilogue targets buf1/buf2

  // ---- epilogue ----
  // issue order (pinned): GB(4), WN-DMA(4) | fence | NZ(16)
  float bs0 = GB[c], bs1 = GB[16 + c], bs2 = GB[32 + c], bs3 = GB[48 + c];
#pragma unroll
  for (int i = 0; i < 4; ++i)
    dma16(wsL + 262144 + i * 4096, ldsL + 16384 + i * 4096);  // WN -> buf1
  asm volatile("" ::: "memory");
  float nz[4][4];
#pragma unroll
  for (int t = 0; t < 4; ++t)
#pragma unroll
    for (int r = 0; r < 4; ++r)
      nz[t][r] = NZ[(size_t)(waveRow + 4 * q + r) * 64 + t * 16 + c];

  float cl[4][4];  // [etile][reg]; element = (row 4q+r, expert 16t+c)
  const float bsv[4] = {bs0, bs1, bs2, bs3};
#pragma unroll
  for (int t = 0; t < 4; ++t)
#pragma unroll
    for (int r = 0; r < 4; ++r)
      cl[t][r] = accH[t][r] + accX[t][r] * INV4096 + bsv[t];

  // clean tile -> own-wave region of buf2, swizzled
  char *cb = lds + 32768 + wv * 4096;
#pragma unroll
  for (int t = 0; t < 4; ++t)
#pragma unroll
    for (int r = 0; r < 4; ++r) {
      int row = 4 * q + r;
      int colf = t * 16 + c;
      int off = row * 256 + ((((colf >> 2) ^ row)) << 4) + ((colf & 3) << 2);
      *reinterpret_cast<float *>(cb + off) = cl[t][r];
    }
  wait_vm<16>();  // drains GB+WN; NZ(16) stays in flight
  BAR();

  // phase 2: raw = clean @ w_noise (split-fp16 MFMA, K=64); WN image in buf1
  f32x4 rH[4] = {};
  f32x4 rX[4] = {};
#pragma unroll
  for (int ks = 0; ks < 2; ++ks) {
    int slot0 = ks * 8 + q * 2;
    f32x4 va = *reinterpret_cast<f32x4 *>(cb + c * 256 + (((slot0 ^ c)) << 4));
    f32x4 vb = *reinterpret_cast<f32x4 *>(cb + c * 256 + ((((slot0 + 1) ^ c)) << 4));
    half8v ah, al;
#pragma unroll
    for (int j = 0; j < 4; ++j) {
      float v = va[j];
      _Float16 hh = (_Float16)v;
      ah[j] = hh;
      al[j] = (_Float16)((v - (float)hh) * 4096.0f);
      float v2 = vb[j];
      _Float16 h2 = (_Float16)v2;
      ah[4 + j] = h2;
      al[4 + j] = (_Float16)((v2 - (float)h2) * 4096.0f);
    }
#pragma unroll
    for (int t = 0; t < 4; ++t) {
      int e = t * 16 + c;
      int off = 16384 + e * 128 + ((((ks * 4 + q) ^ (e & 7))) << 4);
      half8v bh = *reinterpret_cast<half8v *>(lds + off);
      half8v bl = *reinterpret_cast<half8v *>(lds + off + 8192);
      rH[t] = mfma16(ah, bh, rH[t]);
      rX[t] = mfma16(ah, bl, rX[t]);
      rX[t] = mfma16(al, bh, rX[t]);
    }
  }

  float lg[4][4];  // [r][t]
#pragma unroll
  for (int t = 0; t < 4; ++t)
#pragma unroll
    for (int r = 0; r < 4; ++r) {
      float raw = rH[t][r] + rX[t][r] * INV4096;
      float sp = fmaxf(raw, 0.0f) + __logf(1.0f + __expf(-fabsf(raw)));
      lg[r][t] = cl[t][r] + nz[t][r] * (sp + 1e-5f);
    }

#pragma unroll
  for (int r = 0; r < 4; ++r) {
    float v0 = lg[r][0], v1 = lg[r][1], v2 = lg[r][2], v3 = lg[r][3];
    // top-2: in-lane over 4, then xor-shuffle over the 16-lane group
    float a = fmaxf(v0, v1), b_ = fminf(v0, v1);
    float d1 = fmaxf(v2, v3), d2 = fminf(v2, v3);
    float m1 = fmaxf(a, d1);
    float m2 = fmaxf(fminf(a, d1), fmaxf(b_, d2));
#pragma unroll
    for (int s = 1; s <= 8; s <<= 1) {
      float om1 = __shfl_xor(m1, s, 64);
      float om2 = __shfl_xor(m2, s, 64);
      float hi = fmaxf(m1, om1);
      float lo = fminf(m1, om1);
      float sec = (m1 >= om1) ? m2 : om2;
      m2 = fmaxf(lo, sec);
      m1 = hi;
    }
    // softmax(logits)
    float se[4], ssum = 0.f;
#pragma unroll
    for (int t = 0; t < 4; ++t) {
      se[t] = __expf(lg[r][t] - m1);
      ssum += se[t];
    }
#pragma unroll
    for (int s = 1; s <= 8; s <<= 1) ssum += __shfl_xor(ssum, s, 64);
    float inv = 1.0f / ssum;
    float ov[4];
#pragma unroll
    for (int t = 0; t < 4; ++t) {
      float sm = se[t] * inv;
      float vlog = ALPHA * __logf(1.0f + sm);
      float vexp = ALPHA * (__expf(sm) - 1.0f);
      ov[t] = (lg[r][t] < m2) ? vlog : vexp;
    }
    // gates = softmax(out)
    float g = fmaxf(fmaxf(ov[0], ov[1]), fmaxf(ov[2], ov[3]));
#pragma unroll
    for (int s = 1; s <= 8; s <<= 1) g = fmaxf(g, __shfl_xor(g, s, 64));
    float gsum = 0.f;
#pragma unroll
    for (int t = 0; t < 4; ++t) {
      ov[t] = __expf(ov[t] - g);
      gsum += ov[t];
    }
#pragma unroll
    for (int s = 1; s <= 8; s <<= 1) gsum += __shfl_xor(gsum, s, 64);
    float ginv = 1.0f / gsum;
    size_t rowOff = (size_t)(waveRow + 4 * q + r) * 64;
#pragma unroll
    for (int t = 0; t < 4; ++t)
      OUT[rowOff + t * 16 + c] = ov[t] * ginv;
  }
}

extern "C" void kernel_launch(void *const *d_in, const int *in_sizes, int n_in,
                              void *d_out, int out_size, void *d_ws,
                              size_t ws_size, hipStream_t stream) {
  const float *x = (const float *)d_in[0];
  const float *gw = (const float *)d_in[1];
  const float *gb = (const float *)d_in[2];
  const float *wn = (const float *)d_in[3];
  const float *nz = (const float *)d_in[4];
  float *out = (float *)d_out;
  char *ws = (char *)d_ws;
  const int N = in_sizes[0] / 1024;

  hipLaunchKernelGGL(presplit, dim3(68), dim3(256), 0, stream, gw, wn, ws);
  hipLaunchKernelGGL(topk_gating, dim3(N / 64), dim3(256), 0, stream, x, ws,
                     gb, nz, out);
}